// Round 1
// baseline (255.568 us; speedup 1.0000x reference)
//
#include <hip/hip_runtime.h>
#include <cstdint>

#define B_SZ   4
#define E_DIM  16
#define C_INST 24
#define HW_N   262144   // 512*512

#define DELTA_VAR  0.75f
#define DELTA_DIST 2.0f
#define ALPHA_W 1.0f
#define BETA_W  1.0f
#define GAMMA_W 0.001f

// ---------------------------------------------------------------------------
// Pass 1: per-(batch, cluster) sums over E dims + counts.
// Per-wave LDS buckets, lane-parity replicated ([e][2*C], li = lab*2+parity)
// so consecutive labels land in distinct banks and same-address atomic
// serialization multiplicity is halved.
// ---------------------------------------------------------------------------
__global__ __launch_bounds__(256) void pass1_kernel(
    const float* __restrict__ input, const int* __restrict__ target,
    float* __restrict__ sums, float* __restrict__ counts)
{
    __shared__ float ls[4][E_DIM][2 * C_INST];
    __shared__ float lc[4][2 * C_INST];
    const int tid  = threadIdx.x;
    const int wave = tid >> 6;
    const int sub  = tid & 1;
    const int b    = blockIdx.y;

    for (int i = tid; i < 4 * E_DIM * 2 * C_INST; i += 256) ((float*)ls)[i] = 0.f;
    for (int i = tid; i < 4 * 2 * C_INST; i += 256) ((float*)lc)[i] = 0.f;
    __syncthreads();

    const float* src = input + (size_t)b * E_DIM * HW_N;
    const int*   tgt = target + (size_t)b * HW_N;
    const int stride = gridDim.x * 256;
    for (int n = blockIdx.x * 256 + tid; n < HW_N; n += stride) {
        const int li = tgt[n] * 2 + sub;
        unsafeAtomicAdd(&lc[wave][li], 1.0f);
        #pragma unroll
        for (int e = 0; e < E_DIM; ++e) {
            unsafeAtomicAdd(&ls[wave][e][li], src[(size_t)e * HW_N + n]);
        }
    }
    __syncthreads();

    for (int i = tid; i < E_DIM * C_INST; i += 256) {
        const int e = i / C_INST, c = i % C_INST;
        float s = 0.f;
        #pragma unroll
        for (int w = 0; w < 4; ++w) s += ls[w][e][2 * c] + ls[w][e][2 * c + 1];
        unsafeAtomicAdd(&sums[((size_t)b * C_INST + c) * E_DIM + e], s);
    }
    for (int i = tid; i < C_INST; i += 256) {
        float s = 0.f;
        #pragma unroll
        for (int w = 0; w < 4; ++w) s += lc[w][2 * i] + lc[w][2 * i + 1];
        unsafeAtomicAdd(&counts[(size_t)b * C_INST + i], s);
    }
}

// ---------------------------------------------------------------------------
// Pass 2: per-pixel hinged distance to own cluster mean, segment-summed.
// mu staged in LDS as [e][c] (conflict-free across labels for fixed e).
// ---------------------------------------------------------------------------
__global__ __launch_bounds__(256) void pass2_kernel(
    const float* __restrict__ input, const int* __restrict__ target,
    const float* __restrict__ sums, const float* __restrict__ counts,
    float* __restrict__ vars)
{
    __shared__ float mu_l[E_DIM][C_INST];
    __shared__ float lv[4][2 * C_INST];
    const int tid  = threadIdx.x;
    const int wave = tid >> 6;
    const int sub  = tid & 1;
    const int b    = blockIdx.y;

    for (int i = tid; i < E_DIM * C_INST; i += 256) {
        const int e = i / C_INST, c = i % C_INST;
        const float cnt = counts[(size_t)b * C_INST + c];
        mu_l[e][c] = (cnt > 0.f) ? sums[((size_t)b * C_INST + c) * E_DIM + e] / cnt : 0.f;
    }
    for (int i = tid; i < 4 * 2 * C_INST; i += 256) ((float*)lv)[i] = 0.f;
    __syncthreads();

    const float* src = input + (size_t)b * E_DIM * HW_N;
    const int*   tgt = target + (size_t)b * HW_N;
    const int stride = gridDim.x * 256;
    for (int n = blockIdx.x * 256 + tid; n < HW_N; n += stride) {
        const int lab = tgt[n];
        float d2 = 0.f;
        #pragma unroll
        for (int e = 0; e < E_DIM; ++e) {
            const float diff = src[(size_t)e * HW_N + n] - mu_l[e][lab];
            d2 += diff * diff;
        }
        const float h = fmaxf(sqrtf(d2) - DELTA_VAR, 0.f);
        unsafeAtomicAdd(&lv[wave][lab * 2 + sub], h * h);
    }
    __syncthreads();

    for (int i = tid; i < C_INST; i += 256) {
        float s = 0.f;
        #pragma unroll
        for (int w = 0; w < 4; ++w) s += lv[w][2 * i] + lv[w][2 * i + 1];
        unsafeAtomicAdd(&vars[(size_t)b * C_INST + i], s);
    }
}

// ---------------------------------------------------------------------------
// Final: variance + pairwise distance + regularizer -> scalar loss.
// ---------------------------------------------------------------------------
__global__ __launch_bounds__(256) void final_kernel(
    const float* __restrict__ sums, const float* __restrict__ counts,
    const float* __restrict__ vars, float* __restrict__ out)
{
    __shared__ float mu[B_SZ][C_INST][E_DIM];
    __shared__ float red[256];
    const int tid = threadIdx.x;

    for (int i = tid; i < B_SZ * C_INST * E_DIM; i += 256) {
        const int bc = i / E_DIM;
        const float cnt = counts[bc];
        ((float*)mu)[i] = (cnt > 0.f) ? sums[i] / cnt : 0.f;
    }
    __syncthreads();

    float acc = 0.f;
    // variance + regularizer terms over (b, c)
    for (int i = tid; i < B_SZ * C_INST; i += 256) {
        const int b = i / C_INST, c = i % C_INST;
        const float cnt = counts[i];
        const float var = (cnt > 0.f) ? vars[i] / cnt : 0.f;
        float n2 = 0.f;
        #pragma unroll
        for (int e = 0; e < E_DIM; ++e) n2 += mu[b][c][e] * mu[b][c][e];
        acc += (ALPHA_W * var + GAMMA_W * sqrtf(n2)) * (1.0f / (B_SZ * C_INST));
    }
    // pairwise repulsion over (b, c1, c2), diagonal contributes 0
    for (int i = tid; i < B_SZ * C_INST * C_INST; i += 256) {
        const int b  = i / (C_INST * C_INST);
        const int r  = i % (C_INST * C_INST);
        const int c1 = r / C_INST, c2 = r % C_INST;
        if (c1 != c2) {
            float d2 = 0.f;
            #pragma unroll
            for (int e = 0; e < E_DIM; ++e) {
                const float d = mu[b][c1][e] - mu[b][c2][e];
                d2 += d * d;
            }
            const float h = fmaxf(2.0f * DELTA_DIST - sqrtf(d2), 0.f);
            acc += BETA_W * h * h * (1.0f / (B_SZ * C_INST * (C_INST - 1)));
        }
    }

    red[tid] = acc;
    __syncthreads();
    for (int s = 128; s > 0; s >>= 1) {
        if (tid < s) red[tid] += red[tid + s];
        __syncthreads();
    }
    if (tid == 0) out[0] = red[0];
}

extern "C" void kernel_launch(void* const* d_in, const int* in_sizes, int n_in,
                              void* d_out, int out_size, void* d_ws, size_t ws_size,
                              hipStream_t stream)
{
    const float* input  = (const float*)d_in[0];
    const int*   target = (const int*)d_in[1];
    // d_in[2] = n_instances (always 24; hard-coded as C_INST)

    float* sums   = (float*)d_ws;                       // B*C*E
    float* counts = sums + B_SZ * C_INST * E_DIM;       // B*C
    float* vars   = counts + B_SZ * C_INST;             // B*C
    const size_t ws_bytes =
        (size_t)(B_SZ * C_INST * E_DIM + 2 * B_SZ * C_INST) * sizeof(float);
    hipMemsetAsync(d_ws, 0, ws_bytes, stream);

    dim3 grid(256, B_SZ);
    pass1_kernel<<<grid, 256, 0, stream>>>(input, target, sums, counts);
    pass2_kernel<<<grid, 256, 0, stream>>>(input, target, sums, counts, vars);
    final_kernel<<<1, 256, 0, stream>>>(sums, counts, vars, (float*)d_out);
}

// Round 2
// 168.954 us; speedup vs baseline: 1.5126x; 1.5126x over previous
//
#include <hip/hip_runtime.h>
#include <cstdint>

#define B_SZ   4
#define E_DIM  16
#define C_INST 24
#define HW_N   262144   // 512*512

#define DELTA_VAR  0.75f
#define DELTA_DIST 2.0f
#define ALPHA_W 1.0f
#define BETA_W  1.0f
#define GAMMA_W 0.001f

#define P1_BLOCKS 64                            // blocks per (egroup, batch)
#define P1_ITER   (HW_N / (P1_BLOCKS * 256))    // 16
#define P2_BLOCKS 256                           // blocks per batch
#define P2_ITER   (HW_N / (P2_BLOCKS * 256))    // 4

// ---------------------------------------------------------------------------
// Pass 1: segment sums via per-thread register compare-chain (NO LDS atomics).
// Each thread owns 4 embedding dims (eg*4..eg*4+3) and a pixel stride;
// acc[4][24] in VGPRs, one cmp+cndmask per (pixel,c) amortized over 4 fmacs.
// Epilogue: 64-lane shfl_xor butterfly -> LDS stage -> 96 global fp32 atomics.
// ---------------------------------------------------------------------------
__global__ __launch_bounds__(256) void pass1_kernel(
    const float* __restrict__ input, const int* __restrict__ target,
    float* __restrict__ sums, float* __restrict__ counts)
{
    const int tid  = threadIdx.x;
    const int lane = tid & 63;
    const int wv   = tid >> 6;
    const int eg   = blockIdx.y;   // 0..3 -> e base = eg*4
    const int b    = blockIdx.z;

    const float* __restrict__ src = input + ((size_t)b * E_DIM + (size_t)eg * 4) * HW_N;
    const int*   __restrict__ tgt = target + (size_t)b * HW_N;

    float acc[4][C_INST];
    float cnt[C_INST];
    #pragma unroll
    for (int e = 0; e < 4; ++e)
        #pragma unroll
        for (int c = 0; c < C_INST; ++c) acc[e][c] = 0.f;
    #pragma unroll
    for (int c = 0; c < C_INST; ++c) cnt[c] = 0.f;

    int n = blockIdx.x * 256 + tid;
    if (eg == 0) {
        // counts tracked only in the eg==0 group (uniform branch, no divergence)
        #pragma unroll 2
        for (int it = 0; it < P1_ITER; ++it, n += P1_BLOCKS * 256) {
            const int   lab = tgt[n];
            const float x0  = src[n];
            const float x1  = src[HW_N + n];
            const float x2  = src[2 * (size_t)HW_N + n];
            const float x3  = src[3 * (size_t)HW_N + n];
            #pragma unroll
            for (int c = 0; c < C_INST; ++c) {
                const float sel = (lab == c) ? 1.f : 0.f;
                acc[0][c] = fmaf(sel, x0, acc[0][c]);
                acc[1][c] = fmaf(sel, x1, acc[1][c]);
                acc[2][c] = fmaf(sel, x2, acc[2][c]);
                acc[3][c] = fmaf(sel, x3, acc[3][c]);
                cnt[c] += sel;
            }
        }
    } else {
        #pragma unroll 2
        for (int it = 0; it < P1_ITER; ++it, n += P1_BLOCKS * 256) {
            const int   lab = tgt[n];
            const float x0  = src[n];
            const float x1  = src[HW_N + n];
            const float x2  = src[2 * (size_t)HW_N + n];
            const float x3  = src[3 * (size_t)HW_N + n];
            #pragma unroll
            for (int c = 0; c < C_INST; ++c) {
                const float sel = (lab == c) ? 1.f : 0.f;
                acc[0][c] = fmaf(sel, x0, acc[0][c]);
                acc[1][c] = fmaf(sel, x1, acc[1][c]);
                acc[2][c] = fmaf(sel, x2, acc[2][c]);
                acc[3][c] = fmaf(sel, x3, acc[3][c]);
            }
        }
    }

    // 64-lane butterfly: every lane ends with the wave total
    #pragma unroll
    for (int e = 0; e < 4; ++e)
        #pragma unroll
        for (int c = 0; c < C_INST; ++c)
            #pragma unroll
            for (int m = 1; m < 64; m <<= 1)
                acc[e][c] += __shfl_xor(acc[e][c], m, 64);
    if (eg == 0) {
        #pragma unroll
        for (int c = 0; c < C_INST; ++c)
            #pragma unroll
            for (int m = 1; m < 64; m <<= 1)
                cnt[c] += __shfl_xor(cnt[c], m, 64);
    }

    __shared__ float red[4][4 * C_INST];
    __shared__ float redc[4][C_INST];
    if (lane == 0) {
        #pragma unroll
        for (int e = 0; e < 4; ++e)
            #pragma unroll
            for (int c = 0; c < C_INST; ++c)
                red[wv][e * C_INST + c] = acc[e][c];
        if (eg == 0) {
            #pragma unroll
            for (int c = 0; c < C_INST; ++c) redc[wv][c] = cnt[c];
        }
    }
    __syncthreads();

    if (tid < 4 * C_INST) {
        const int e = tid / C_INST, c = tid % C_INST;
        const float s = red[0][tid] + red[1][tid] + red[2][tid] + red[3][tid];
        unsafeAtomicAdd(&sums[((size_t)b * C_INST + c) * E_DIM + eg * 4 + e], s);
    }
    if (eg == 0 && tid < C_INST) {
        const float s = redc[0][tid] + redc[1][tid] + redc[2][tid] + redc[3][tid];
        unsafeAtomicAdd(&counts[b * C_INST + tid], s);
    }
}

// ---------------------------------------------------------------------------
// Pass 2: per-pixel hinged distance to own mean. mu in LDS [e][c]
// (24 consecutive addrs -> distinct banks; duplicates broadcast => no
// conflicts). Hinge^2 accumulated in per-thread registers via compare-chain,
// butterfly-reduced, one global atomic per (block, c).
// ---------------------------------------------------------------------------
__global__ __launch_bounds__(256) void pass2_kernel(
    const float* __restrict__ input, const int* __restrict__ target,
    const float* __restrict__ sums, const float* __restrict__ counts,
    float* __restrict__ vars)
{
    __shared__ float mu_l[E_DIM][C_INST];
    const int tid  = threadIdx.x;
    const int lane = tid & 63;
    const int wv   = tid >> 6;
    const int b    = blockIdx.y;

    for (int i = tid; i < E_DIM * C_INST; i += 256) {
        const int e = i / C_INST, c = i % C_INST;
        const float cnv = counts[b * C_INST + c];
        mu_l[e][c] = (cnv > 0.f) ? sums[((size_t)b * C_INST + c) * E_DIM + e] / cnv : 0.f;
    }
    __syncthreads();

    const float* __restrict__ src = input + (size_t)b * E_DIM * HW_N;
    const int*   __restrict__ tgt = target + (size_t)b * HW_N;

    float vacc[C_INST];
    #pragma unroll
    for (int c = 0; c < C_INST; ++c) vacc[c] = 0.f;

    int n = blockIdx.x * 256 + tid;
    #pragma unroll 2
    for (int it = 0; it < P2_ITER; ++it, n += P2_BLOCKS * 256) {
        const int lab = tgt[n];
        float x[E_DIM];
        #pragma unroll
        for (int e = 0; e < E_DIM; ++e) x[e] = src[(size_t)e * HW_N + n];
        float d2 = 0.f;
        #pragma unroll
        for (int e = 0; e < E_DIM; ++e) {
            const float diff = x[e] - mu_l[e][lab];
            d2 = fmaf(diff, diff, d2);
        }
        const float h  = fmaxf(sqrtf(d2) - DELTA_VAR, 0.f);
        const float h2 = h * h;
        #pragma unroll
        for (int c = 0; c < C_INST; ++c) {
            const float sel = (lab == c) ? 1.f : 0.f;
            vacc[c] = fmaf(sel, h2, vacc[c]);
        }
    }

    #pragma unroll
    for (int c = 0; c < C_INST; ++c)
        #pragma unroll
        for (int m = 1; m < 64; m <<= 1)
            vacc[c] += __shfl_xor(vacc[c], m, 64);

    __shared__ float redv[4][C_INST];
    if (lane == 0) {
        #pragma unroll
        for (int c = 0; c < C_INST; ++c) redv[wv][c] = vacc[c];
    }
    __syncthreads();
    if (tid < C_INST) {
        const float s = redv[0][tid] + redv[1][tid] + redv[2][tid] + redv[3][tid];
        unsafeAtomicAdd(&vars[b * C_INST + tid], s);
    }
}

// ---------------------------------------------------------------------------
// Final: variance + pairwise distance + regularizer -> scalar loss.
// ---------------------------------------------------------------------------
__global__ __launch_bounds__(256) void final_kernel(
    const float* __restrict__ sums, const float* __restrict__ counts,
    const float* __restrict__ vars, float* __restrict__ out)
{
    __shared__ float mu[B_SZ][C_INST][E_DIM];
    __shared__ float red[256];
    const int tid = threadIdx.x;

    for (int i = tid; i < B_SZ * C_INST * E_DIM; i += 256) {
        const int bc = i / E_DIM;
        const float cnv = counts[bc];
        ((float*)mu)[i] = (cnv > 0.f) ? sums[i] / cnv : 0.f;
    }
    __syncthreads();

    float acc = 0.f;
    for (int i = tid; i < B_SZ * C_INST; i += 256) {
        const int b = i / C_INST, c = i % C_INST;
        const float cnv = counts[i];
        const float var = (cnv > 0.f) ? vars[i] / cnv : 0.f;
        float n2 = 0.f;
        #pragma unroll
        for (int e = 0; e < E_DIM; ++e) n2 += mu[b][c][e] * mu[b][c][e];
        acc += (ALPHA_W * var + GAMMA_W * sqrtf(n2)) * (1.0f / (B_SZ * C_INST));
    }
    for (int i = tid; i < B_SZ * C_INST * C_INST; i += 256) {
        const int b  = i / (C_INST * C_INST);
        const int r  = i % (C_INST * C_INST);
        const int c1 = r / C_INST, c2 = r % C_INST;
        if (c1 != c2) {
            float d2 = 0.f;
            #pragma unroll
            for (int e = 0; e < E_DIM; ++e) {
                const float d = mu[b][c1][e] - mu[b][c2][e];
                d2 += d * d;
            }
            const float h = fmaxf(2.0f * DELTA_DIST - sqrtf(d2), 0.f);
            acc += BETA_W * h * h * (1.0f / (B_SZ * C_INST * (C_INST - 1)));
        }
    }

    red[tid] = acc;
    __syncthreads();
    for (int s = 128; s > 0; s >>= 1) {
        if (tid < s) red[tid] += red[tid + s];
        __syncthreads();
    }
    if (tid == 0) out[0] = red[0];
}

extern "C" void kernel_launch(void* const* d_in, const int* in_sizes, int n_in,
                              void* d_out, int out_size, void* d_ws, size_t ws_size,
                              hipStream_t stream)
{
    const float* input  = (const float*)d_in[0];
    const int*   target = (const int*)d_in[1];

    float* sums   = (float*)d_ws;                       // B*C*E
    float* counts = sums + B_SZ * C_INST * E_DIM;       // B*C
    float* vars   = counts + B_SZ * C_INST;             // B*C
    const size_t ws_bytes =
        (size_t)(B_SZ * C_INST * E_DIM + 2 * B_SZ * C_INST) * sizeof(float);
    hipMemsetAsync(d_ws, 0, ws_bytes, stream);

    pass1_kernel<<<dim3(P1_BLOCKS, 4, B_SZ), 256, 0, stream>>>(input, target, sums, counts);
    pass2_kernel<<<dim3(P2_BLOCKS, B_SZ), 256, 0, stream>>>(input, target, sums, counts, vars);
    final_kernel<<<1, 256, 0, stream>>>(sums, counts, vars, (float*)d_out);
}